// Round 10
// baseline (896.412 us; speedup 1.0000x reference)
//
#include <hip/hip_runtime.h>
#include <hip/hip_bf16.h>
#include <math.h>

#define N_NODES 50000
#define N_EDGES 1600000
#define NFEAT   512
#define NHID    256
#define NCLASS  40
#define HCOLS   1536   // 512 + 4*256

typedef __attribute__((ext_vector_type(8))) short bf16x8s;
typedef __attribute__((ext_vector_type(4))) float f32x4;

__device__ __forceinline__ ushort f2bf(float f) {
    uint u = __builtin_bit_cast(uint, f);
    uint r = (u + 0x7fffu + ((u >> 16) & 1u)) >> 16;
    return (ushort)r;
}
__device__ __forceinline__ float bf2f(ushort u) {
    uint t = (uint)u << 16;
    return __builtin_bit_cast(float, t);
}

// ---------------------------------------------------------------------------
// convert x (f32) into Hb[:, 0:512] (bf16, stride 1536)
__global__ __launch_bounds__(256) void copy_x_bf16_kernel(const float4* __restrict__ x4,
                                                          ushort* __restrict__ Hb) {
    const int total = N_NODES * (NFEAT / 4);      // 6.4M float4
    for (int idx = blockIdx.x * blockDim.x + threadIdx.x; idx < total;
         idx += gridDim.x * blockDim.x) {
        int node = idx >> 7;          // /128
        int j    = idx & 127;
        float4 v = x4[idx];
        ushort4 o;
        o.x = f2bf(v.x); o.y = f2bf(v.y); o.z = f2bf(v.z); o.w = f2bf(v.w);
        *(ushort4*)&Hb[(size_t)node * HCOLS + j * 4] = o;
    }
}

// all weight transposes (f32 -> bf16) in one kernel; Wt_out rows 40..127 zeroed
__global__ __launch_bounds__(256) void convert_weights_kernel(
        const float* __restrict__ W0, const float* __restrict__ W1,
        const float* __restrict__ W2, const float* __restrict__ W3,
        const float* __restrict__ Wout,
        ushort* __restrict__ T0, ushort* __restrict__ T1,
        ushort* __restrict__ T2, ushort* __restrict__ T3,
        ushort* __restrict__ Tout) {
    const int S0 = 512 * 256, S1 = 768 * 256, S2 = 1024 * 256, S3 = 1280 * 256;
    const int S4 = 128 * HCOLS;
    const int total = S0 + S1 + S2 + S3 + S4;
    for (int idx = blockIdx.x * blockDim.x + threadIdx.x; idx < total;
         idx += gridDim.x * blockDim.x) {
        int t = idx;
        if (t < S0) {
            int n = t / 512, k = t - n * 512;
            T0[t] = f2bf(W0[(size_t)k * NHID + n]);
        } else if ((t -= S0) < S1) {
            int n = t / 768, k = t - n * 768;
            T1[t] = f2bf(W1[(size_t)k * NHID + n]);
        } else if ((t -= S1) < S2) {
            int n = t / 1024, k = t - n * 1024;
            T2[t] = f2bf(W2[(size_t)k * NHID + n]);
        } else if ((t -= S2) < S3) {
            int n = t / 1280, k = t - n * 1280;
            T3[t] = f2bf(W3[(size_t)k * NHID + n]);
        } else {
            t -= S3;
            int n = t / HCOLS, k = t - n * HCOLS;
            Tout[t] = (n < NCLASS) ? f2bf(Wout[(size_t)k * NCLASS + n]) : (ushort)0;
        }
    }
}

// ---------------------------------------------------------------------------
__global__ __launch_bounds__(256) void hist_kernel(const int* __restrict__ dst,
                                                   int* __restrict__ cnt) {
    int i = blockIdx.x * 256 + threadIdx.x;
    if (i < N_EDGES) atomicAdd(&cnt[dst[i]], 1);
}

// single-block exclusive scan via wave shuffles
__global__ __launch_bounds__(1024) void scan_kernel(const int* __restrict__ cnt,
                                                    int* __restrict__ row_ptr) {
    __shared__ int wsum[16];
    __shared__ int carry_s;
    const int tid = threadIdx.x;
    const int lane = tid & 63;
    const int w = tid >> 6;
    if (tid == 0) { carry_s = 0; row_ptr[0] = 0; }
    __syncthreads();
    for (int base = 0; base < N_NODES; base += 1024) {
        int i = base + tid;
        int v = (i < N_NODES) ? cnt[i] : 0;
        int sc = v;
        #pragma unroll
        for (int off = 1; off < 64; off <<= 1) {
            int t = __shfl_up(sc, off);
            if (lane >= off) sc += t;
        }
        if (lane == 63) wsum[w] = sc;
        __syncthreads();
        if (w == 0 && lane < 16) {
            int t = wsum[lane];
            int s2 = t;
            #pragma unroll
            for (int off = 1; off < 16; off <<= 1) {
                int u = __shfl_up(s2, off);
                if (lane >= off) s2 += u;
            }
            wsum[lane] = s2 - t;
        }
        __syncthreads();
        int incl = sc + wsum[w] + carry_s;
        if (i < N_NODES) row_ptr[i + 1] = incl;
        __syncthreads();
        if (tid == 1023) carry_s = incl;
        __syncthreads();
    }
}

// scatter edges into CSR order as packed (src, val_bits) uint2 — ONE 8B store
__global__ __launch_bounds__(256) void scatter_kernel(const int* __restrict__ src,
                                                      const int* __restrict__ dst,
                                                      const float* __restrict__ val,
                                                      const int* __restrict__ row_ptr,
                                                      int* __restrict__ cnt,
                                                      uint2* __restrict__ edges) {
    int i = blockIdx.x * 256 + threadIdx.x;
    if (i < N_EDGES) {
        int d   = dst[i];
        int pos = row_ptr[d] + atomicAdd(&cnt[d], 1);
        uint2 p;
        p.x = (uint)src[i];
        p.y = __builtin_bit_cast(uint, val[i]);
        edges[pos] = p;
    }
}

// ---------------------------------------------------------------------------
// bf16 MFMA GEMM, 128x256 tile, 512 threads (8 waves 2x4, each 64x64),
// double-buffered with COUNTED vmcnt + RAW s_barrier (T4): the t+1 tile's 3
// global_load_lds stay in flight ACROSS the barrier; each K-step waits only
// vmcnt(3) (its own tile's loads). __syncthreads() was draining vmcnt(0) at
// every barrier (m97 ceiling), killing the R9 dbuf pipeline.
__global__ __launch_bounds__(512) void gemm_bf16_wide(const ushort* __restrict__ A, int lda,
                                                      const ushort* __restrict__ Bt, int ldb,
                                                      ushort* __restrict__ C, int ldc,
                                                      int M, int K) {
    __shared__ short As[2][128 * 32];
    __shared__ short Bs[2][256 * 32];
    const int tid  = threadIdx.x;
    const int lane = tid & 63;
    const int wid  = tid >> 6;
    const int wr   = wid >> 2;          // 0..1
    const int wc   = wid & 3;           // 0..3
    const int bm   = blockIdx.x * 128;

    f32x4 acc[4][4] = {};
    const int r0 = tid >> 2, ko = (tid & 3) * 8;   // r0: 0..127, ko: 0/8/16/24

    const ushort* gA  = A  + (size_t)(bm + r0) * lda + ko;
    const ushort* gB0 = Bt + (size_t)r0 * ldb + ko;
    const ushort* gB1 = Bt + (size_t)(128 + r0) * ldb + ko;

#define STAGE_WIDE(buf, kk) do { \
    __builtin_amdgcn_global_load_lds((const __attribute__((address_space(1))) void*)(gA + (kk)), \
        (__attribute__((address_space(3))) void*)&As[buf][tid * 8], 16, 0, 0); \
    __builtin_amdgcn_global_load_lds((const __attribute__((address_space(1))) void*)(gB0 + (kk)), \
        (__attribute__((address_space(3))) void*)&Bs[buf][tid * 8], 16, 0, 0); \
    __builtin_amdgcn_global_load_lds((const __attribute__((address_space(1))) void*)(gB1 + (kk)), \
        (__attribute__((address_space(3))) void*)&Bs[buf][(tid + 512) * 8], 16, 0, 0); \
} while (0)

    STAGE_WIDE(0, 0);

    const int kg = (lane >> 4) * 8;
    const int rr = lane & 15;
    int cur = 0;
    for (int k0 = 0; k0 < K; k0 += 32) {
        if (k0 + 32 < K) {
            STAGE_WIDE(cur ^ 1, k0 + 32);                  // 3 loads for t+1
            asm volatile("s_waitcnt vmcnt(3)" ::: "memory"); // t's 3 loads done
        } else {
            asm volatile("s_waitcnt vmcnt(0)" ::: "memory"); // last tile: drain
        }
        __builtin_amdgcn_s_barrier();                      // publish buf cur
        __builtin_amdgcn_sched_barrier(0);                 // pin ds_reads after
        bf16x8s a[4], b[4];
        #pragma unroll
        for (int i = 0; i < 4; ++i)
            a[i] = *(const bf16x8s*)&As[cur][(wr * 64 + i * 16 + rr) * 32 + kg];
        #pragma unroll
        for (int j = 0; j < 4; ++j)
            b[j] = *(const bf16x8s*)&Bs[cur][(wc * 64 + j * 16 + rr) * 32 + kg];
        #pragma unroll
        for (int i = 0; i < 4; ++i)
            #pragma unroll
            for (int j = 0; j < 4; ++j)
                acc[i][j] = __builtin_amdgcn_mfma_f32_16x16x32_bf16(a[i], b[j], acc[i][j], 0, 0, 0);
        __builtin_amdgcn_s_barrier();                      // all reads of cur done
        cur ^= 1;
    }
#undef STAGE_WIDE

    // epilogue: D row=(lane>>4)*4+r, col=lane&15  [m89 verified mapping]
    const int rowg = (lane >> 4) * 4;
    const int colg = lane & 15;
    #pragma unroll
    for (int i = 0; i < 4; ++i) {
        #pragma unroll
        for (int j = 0; j < 4; ++j) {
            #pragma unroll
            for (int r = 0; r < 4; ++r) {
                int row = bm + wr * 64 + i * 16 + rowg + r;
                int col = wc * 64 + j * 16 + colg;
                if (row < M) C[(size_t)row * ldc + col] = f2bf(acc[i][j][r]);
            }
        }
    }
}

// bf16 MFMA GEMM (m97 structure): 128x128 tile — used for the out layer only
__global__ __launch_bounds__(256) void gemm_bf16(const ushort* __restrict__ A, int lda,
                                                 const ushort* __restrict__ Bt, int ldb,
                                                 ushort* __restrict__ C, int ldc,
                                                 int M, int K, int Nc) {
    __shared__ short As[128 * 32];
    __shared__ short Bs[128 * 32];
    const int tid  = threadIdx.x;
    const int lane = tid & 63;
    const int wid  = tid >> 6;
    const int wr   = wid >> 1;
    const int wc   = wid & 1;
    const int bm   = blockIdx.x * 128;
    const int bn   = blockIdx.y * 128;

    f32x4 acc[4][4] = {};
    const int r0 = tid >> 2, ko = (tid & 3) * 8;

    for (int k0 = 0; k0 < K; k0 += 32) {
        {
            const ushort* g0 = A + (size_t)(bm + r0) * lda + k0 + ko;
            const ushort* g1 = A + (size_t)(bm + 64 + r0) * lda + k0 + ko;
            __builtin_amdgcn_global_load_lds((const __attribute__((address_space(1))) void*)g0,
                                             (__attribute__((address_space(3))) void*)&As[tid * 8], 16, 0, 0);
            __builtin_amdgcn_global_load_lds((const __attribute__((address_space(1))) void*)g1,
                                             (__attribute__((address_space(3))) void*)&As[(tid + 256) * 8], 16, 0, 0);
        }
        {
            const ushort* g0 = Bt + (size_t)(bn + r0) * ldb + k0 + ko;
            const ushort* g1 = Bt + (size_t)(bn + 64 + r0) * ldb + k0 + ko;
            __builtin_amdgcn_global_load_lds((const __attribute__((address_space(1))) void*)g0,
                                             (__attribute__((address_space(3))) void*)&Bs[tid * 8], 16, 0, 0);
            __builtin_amdgcn_global_load_lds((const __attribute__((address_space(1))) void*)g1,
                                             (__attribute__((address_space(3))) void*)&Bs[(tid + 256) * 8], 16, 0, 0);
        }
        __syncthreads();

        const int kg = (lane >> 4) * 8;
        const int rr = lane & 15;
        bf16x8s a[4], b[4];
        #pragma unroll
        for (int i = 0; i < 4; ++i)
            a[i] = *(const bf16x8s*)&As[(wr * 64 + i * 16 + rr) * 32 + kg];
        #pragma unroll
        for (int j = 0; j < 4; ++j)
            b[j] = *(const bf16x8s*)&Bs[(wc * 64 + j * 16 + rr) * 32 + kg];
        #pragma unroll
        for (int i = 0; i < 4; ++i)
            #pragma unroll
            for (int j = 0; j < 4; ++j)
                acc[i][j] = __builtin_amdgcn_mfma_f32_16x16x32_bf16(a[i], b[j], acc[i][j], 0, 0, 0);
        __syncthreads();
    }

    const int rowg = (lane >> 4) * 4;
    const int colg = lane & 15;
    #pragma unroll
    for (int i = 0; i < 4; ++i) {
        #pragma unroll
        for (int j = 0; j < 4; ++j) {
            #pragma unroll
            for (int r = 0; r < 4; ++r) {
                int row = bm + wr * 64 + i * 16 + rowg + r;
                int col = bn + wc * 64 + j * 16 + colg;
                if (row < M && col < Nc) C[(size_t)row * ldc + col] = f2bf(acc[i][j][r]);
            }
        }
    }
}

// ---------------------------------------------------------------------------
// CSR spmm, 256-wide bf16 features, one wave/node.
// CLOSED at ~105 us: random-gather L2-miss floor (350 MB @ ~3.6 TB/s).
// Col-split, XCD-pinning, src-ordering, explicit SW pipeline all falsified.
__global__ __launch_bounds__(256) void spmm256_tanh_kernel(const int* __restrict__ row_ptr,
                                                           const uint2* __restrict__ edges,
                                                           const ushort* __restrict__ Zb, // [N,256] bf16
                                                           const float* __restrict__ bias,
                                                           ushort* __restrict__ out,      // Hb + col_off
                                                           int out_stride) {
    int node = blockIdx.x * 4 + (threadIdx.x >> 6);
    if (node >= N_NODES) return;
    int lane = threadIdx.x & 63;
    int s = row_ptr[node], e = row_ptr[node + 1];
    const ushort4* Z4 = (const ushort4*)Zb;   // 4 cols / lane
    float ax = 0.f, ay = 0.f, az = 0.f, aw = 0.f;
    int i = s;

    if (e - s >= 16) {
        uint2   ed[8];
        float   vaA[8], vaB[8];
        ushort4 xvA[8], xvB[8];
        #pragma unroll
        for (int u = 0; u < 8; ++u) ed[u] = edges[i + u];
        #pragma unroll
        for (int u = 0; u < 8; ++u) {
            vaA[u] = __builtin_bit_cast(float, ed[u].y);
            xvA[u] = Z4[(size_t)ed[u].x * 64 + lane];
        }
        #pragma unroll
        for (int u = 0; u < 8; ++u) ed[u] = edges[i + 8 + u];

        while (i + 32 <= e) {
            #pragma unroll
            for (int u = 0; u < 8; ++u) {
                vaB[u] = __builtin_bit_cast(float, ed[u].y);
                xvB[u] = Z4[(size_t)ed[u].x * 64 + lane];
            }
            #pragma unroll
            for (int u = 0; u < 8; ++u) ed[u] = edges[i + 16 + u];
            #pragma unroll
            for (int u = 0; u < 8; ++u) {
                ax += vaA[u] * bf2f(xvA[u].x); ay += vaA[u] * bf2f(xvA[u].y);
                az += vaA[u] * bf2f(xvA[u].z); aw += vaA[u] * bf2f(xvA[u].w);
            }
            #pragma unroll
            for (int u = 0; u < 8; ++u) {
                vaA[u] = __builtin_bit_cast(float, ed[u].y);
                xvA[u] = Z4[(size_t)ed[u].x * 64 + lane];
            }
            #pragma unroll
            for (int u = 0; u < 8; ++u) ed[u] = edges[i + 24 + u];
            #pragma unroll
            for (int u = 0; u < 8; ++u) {
                ax += vaB[u] * bf2f(xvB[u].x); ay += vaB[u] * bf2f(xvB[u].y);
                az += vaB[u] * bf2f(xvB[u].z); aw += vaB[u] * bf2f(xvB[u].w);
            }
            i += 16;
        }
        #pragma unroll
        for (int u = 0; u < 8; ++u) {
            vaB[u] = __builtin_bit_cast(float, ed[u].y);
            xvB[u] = Z4[(size_t)ed[u].x * 64 + lane];
        }
        #pragma unroll
        for (int u = 0; u < 8; ++u) {
            ax += vaA[u] * bf2f(xvA[u].x); ay += vaA[u] * bf2f(xvA[u].y);
            az += vaA[u] * bf2f(xvA[u].z); aw += vaA[u] * bf2f(xvA[u].w);
        }
        #pragma unroll
        for (int u = 0; u < 8; ++u) {
            ax += vaB[u] * bf2f(xvB[u].x); ay += vaB[u] * bf2f(xvB[u].y);
            az += vaB[u] * bf2f(xvB[u].z); aw += vaB[u] * bf2f(xvB[u].w);
        }
        i += 16;
    }
    for (; i + 4 <= e; i += 4) {
        uint2 ed[4]; ushort4 xv[4];
        #pragma unroll
        for (int u = 0; u < 4; ++u) ed[u] = edges[i + u];
        #pragma unroll
        for (int u = 0; u < 4; ++u) xv[u] = Z4[(size_t)ed[u].x * 64 + lane];
        #pragma unroll
        for (int u = 0; u < 4; ++u) {
            float v = __builtin_bit_cast(float, ed[u].y);
            ax += v * bf2f(xv[u].x); ay += v * bf2f(xv[u].y);
            az += v * bf2f(xv[u].z); aw += v * bf2f(xv[u].w);
        }
    }
    for (; i < e; ++i) {
        uint2 ed = edges[i];
        float v = __builtin_bit_cast(float, ed.y);
        ushort4 x0 = Z4[(size_t)ed.x * 64 + lane];
        ax += v * bf2f(x0.x); ay += v * bf2f(x0.y);
        az += v * bf2f(x0.z); aw += v * bf2f(x0.w);
    }
    float4 b = ((const float4*)bias)[lane];
    ushort4 o;
    o.x = f2bf(tanhf(ax + b.x)); o.y = f2bf(tanhf(ay + b.y));
    o.z = f2bf(tanhf(az + b.z)); o.w = f2bf(tanhf(aw + b.w));
    *(ushort4*)&out[(size_t)node * out_stride + lane * 4] = o;
}

// out-layer: spmm (Zout bf16, stride 64, cols 40..63 zero) + bias + log_softmax.
__global__ __launch_bounds__(256) void spmm_out_lsm_kernel(const int* __restrict__ row_ptr,
                                                           const uint2* __restrict__ edges,
                                                           const ushort* __restrict__ Zb, // [N,64]
                                                           const float* __restrict__ bias,
                                                           float* __restrict__ out) { // [N,40]
    int node = blockIdx.x * 4 + (threadIdx.x >> 6);
    if (node >= N_NODES) return;
    int lane = threadIdx.x & 63;
    int e8 = lane >> 3;     // edge slot 0..7
    int cg = lane & 7;      // col group: cols cg*8 .. cg*8+7
    int s = row_ptr[node], e = row_ptr[node + 1];
    float acc[8] = {};
    int i = s;
    for (; i + 8 <= e; i += 8) {
        uint2 ed = edges[i + e8];
        float v  = __builtin_bit_cast(float, ed.y);
        bf16x8s x = *(const bf16x8s*)&Zb[(size_t)ed.x * 64 + cg * 8];
        #pragma unroll
        for (int u = 0; u < 8; ++u) acc[u] += v * bf2f((ushort)x[u]);
    }
    if (i + e8 < e) {
        uint2 ed = edges[i + e8];
        float v  = __builtin_bit_cast(float, ed.y);
        bf16x8s x = *(const bf16x8s*)&Zb[(size_t)ed.x * 64 + cg * 8];
        #pragma unroll
        for (int u = 0; u < 8; ++u) acc[u] += v * bf2f((ushort)x[u]);
    }
    #pragma unroll
    for (int off = 8; off < 64; off <<= 1)
        #pragma unroll
        for (int u = 0; u < 8; ++u) acc[u] += __shfl_xor(acc[u], off);
    float m = -INFINITY;
    #pragma unroll
    for (int u = 0; u < 8; ++u) {
        int col = cg * 8 + u;
        if (col < NCLASS) { acc[u] += bias[col]; m = fmaxf(m, acc[u]); }
    }
    #pragma unroll
    for (int off = 1; off < 8; off <<= 1) m = fmaxf(m, __shfl_xor(m, off));
    float ss = 0.f;
    #pragma unroll
    for (int u = 0; u < 8; ++u) {
        int col = cg * 8 + u;
        if (col < NCLASS) ss += expf(acc[u] - m);
    }
    #pragma unroll
    for (int off = 1; off < 8; off <<= 1) ss += __shfl_xor(ss, off);
    float lse = logf(ss);
    if (e8 == 0) {
        #pragma unroll
        for (int u = 0; u < 8; ++u) {
            int col = cg * 8 + u;
            if (col < NCLASS) out[(size_t)node * NCLASS + col] = acc[u] - m - lse;
        }
    }
}

// ---------------------------------------------------------------------------
extern "C" void kernel_launch(void* const* d_in, const int* in_sizes, int n_in,
                              void* d_out, int out_size, void* d_ws, size_t ws_size,
                              hipStream_t stream) {
    const float* x        = (const float*)d_in[0];
    const float* edge_val = (const float*)d_in[1];
    const int*   edge_src = (const int*)d_in[2];
    const int*   edge_dst = (const int*)d_in[3];
    const float* W[4]     = {(const float*)d_in[4], (const float*)d_in[6],
                             (const float*)d_in[8], (const float*)d_in[10]};
    const float* bvec[4]  = {(const float*)d_in[5], (const float*)d_in[7],
                             (const float*)d_in[9], (const float*)d_in[11]};
    const float* W_out    = (const float*)d_in[12];
    const float* b_out    = (const float*)d_in[13];
    float* out = (float*)d_out;

    // workspace carve-up (bytes)
    char* ws = (char*)d_ws;
    ushort* Hb     = (ushort*)ws;                          // 153.6 MB
    ushort* Zb     = (ushort*)(ws + 153600000);            // 25.6 MB
    ushort* Zoutb  = (ushort*)(ws + 179200000);            // 6.4 MB
    ushort* Wt[4]  = {(ushort*)(ws + 185600000),
                      (ushort*)(ws + 185862144),
                      (ushort*)(ws + 186255360),
                      (ushort*)(ws + 186779648)};
    ushort* Wt_out = (ushort*)(ws + 187435008);
    uint2*  edges  = (uint2*) (ws + 187828224);            // 12.8 MB packed (src,val)
    int*    row_ptr= (int*)   (ws + 200628224);
    int*    cnt    = (int*)   (ws + 200828228);

    // 1. CSR build
    hipMemsetAsync(cnt, 0, N_NODES * sizeof(int), stream);
    hist_kernel<<<(N_EDGES + 255) / 256, 256, 0, stream>>>(edge_dst, cnt);
    scan_kernel<<<1, 1024, 0, stream>>>(cnt, row_ptr);
    hipMemsetAsync(cnt, 0, N_NODES * sizeof(int), stream);
    scatter_kernel<<<(N_EDGES + 255) / 256, 256, 0, stream>>>(
        edge_src, edge_dst, edge_val, row_ptr, cnt, edges);

    // 2. weights -> bf16 transposed, x -> Hb
    convert_weights_kernel<<<2048, 256, 0, stream>>>(W[0], W[1], W[2], W[3], W_out,
                                                     Wt[0], Wt[1], Wt[2], Wt[3], Wt_out);
    copy_x_bf16_kernel<<<4096, 256, 0, stream>>>((const float4*)x, Hb);

    // 3. snowball layers — 128x256 dbuf+counted-vmcnt GEMM, A read once per layer
    for (int k = 0; k < 4; ++k) {
        int fan_in = NFEAT + k * NHID;
        gemm_bf16_wide<<<(N_NODES + 127) / 128, 512, 0, stream>>>(
            Hb, HCOLS, Wt[k], fan_in, Zb, NHID, N_NODES, fan_in);
        spmm256_tanh_kernel<<<(N_NODES + 3) / 4, 256, 0, stream>>>(
            row_ptr, edges, Zb, bvec[k], Hb + NFEAT + k * NHID, HCOLS);
    }

    // 4. out layer
    {
        dim3 g((N_NODES + 127) / 128, 1);
        gemm_bf16<<<g, 256, 0, stream>>>(Hb, HCOLS, Wt_out, HCOLS, Zoutb, 64,
                                         N_NODES, HCOLS, 64);
        spmm_out_lsm_kernel<<<(N_NODES + 3) / 4, 256, 0, stream>>>(
            row_ptr, edges, Zoutb, b_out, out);
    }
    (void)in_sizes; (void)n_in; (void)out_size; (void)ws_size;
}

// Round 11
// 884.455 us; speedup vs baseline: 1.0135x; 1.0135x over previous
//
#include <hip/hip_runtime.h>
#include <hip/hip_bf16.h>
#include <math.h>

#define N_NODES 50000
#define N_EDGES 1600000
#define NFEAT   512
#define NHID    256
#define NCLASS  40
#define HCOLS   1536   // 512 + 4*256

typedef __attribute__((ext_vector_type(8))) short bf16x8s;
typedef __attribute__((ext_vector_type(4))) float f32x4;

__device__ __forceinline__ ushort f2bf(float f) {
    uint u = __builtin_bit_cast(uint, f);
    uint r = (u + 0x7fffu + ((u >> 16) & 1u)) >> 16;
    return (ushort)r;
}
__device__ __forceinline__ float bf2f(ushort u) {
    uint t = (uint)u << 16;
    return __builtin_bit_cast(float, t);
}

// ---------------------------------------------------------------------------
// convert x (f32) into Hb[:, 0:512] (bf16, stride 1536)
__global__ __launch_bounds__(256) void copy_x_bf16_kernel(const float4* __restrict__ x4,
                                                          ushort* __restrict__ Hb) {
    const int total = N_NODES * (NFEAT / 4);      // 6.4M float4
    for (int idx = blockIdx.x * blockDim.x + threadIdx.x; idx < total;
         idx += gridDim.x * blockDim.x) {
        int node = idx >> 7;          // /128
        int j    = idx & 127;
        float4 v = x4[idx];
        ushort4 o;
        o.x = f2bf(v.x); o.y = f2bf(v.y); o.z = f2bf(v.z); o.w = f2bf(v.w);
        *(ushort4*)&Hb[(size_t)node * HCOLS + j * 4] = o;
    }
}

// all weight transposes (f32 -> bf16) in one kernel; Wt_out rows 40..63 zeroed
__global__ __launch_bounds__(256) void convert_weights_kernel(
        const float* __restrict__ W0, const float* __restrict__ W1,
        const float* __restrict__ W2, const float* __restrict__ W3,
        const float* __restrict__ Wout,
        ushort* __restrict__ T0, ushort* __restrict__ T1,
        ushort* __restrict__ T2, ushort* __restrict__ T3,
        ushort* __restrict__ Tout) {
    const int S0 = 512 * 256, S1 = 768 * 256, S2 = 1024 * 256, S3 = 1280 * 256;
    const int S4 = 64 * HCOLS;
    const int total = S0 + S1 + S2 + S3 + S4;
    for (int idx = blockIdx.x * blockDim.x + threadIdx.x; idx < total;
         idx += gridDim.x * blockDim.x) {
        int t = idx;
        if (t < S0) {
            int n = t / 512, k = t - n * 512;
            T0[t] = f2bf(W0[(size_t)k * NHID + n]);
        } else if ((t -= S0) < S1) {
            int n = t / 768, k = t - n * 768;
            T1[t] = f2bf(W1[(size_t)k * NHID + n]);
        } else if ((t -= S1) < S2) {
            int n = t / 1024, k = t - n * 1024;
            T2[t] = f2bf(W2[(size_t)k * NHID + n]);
        } else if ((t -= S2) < S3) {
            int n = t / 1280, k = t - n * 1280;
            T3[t] = f2bf(W3[(size_t)k * NHID + n]);
        } else {
            t -= S3;
            int n = t / HCOLS, k = t - n * HCOLS;
            Tout[t] = (n < NCLASS) ? f2bf(Wout[(size_t)k * NCLASS + n]) : (ushort)0;
        }
    }
}

// ---------------------------------------------------------------------------
__global__ __launch_bounds__(256) void hist_kernel(const int* __restrict__ dst,
                                                   int* __restrict__ cnt) {
    int i = blockIdx.x * 256 + threadIdx.x;
    if (i < N_EDGES) atomicAdd(&cnt[dst[i]], 1);
}

// single-block exclusive scan via wave shuffles
__global__ __launch_bounds__(1024) void scan_kernel(const int* __restrict__ cnt,
                                                    int* __restrict__ row_ptr) {
    __shared__ int wsum[16];
    __shared__ int carry_s;
    const int tid = threadIdx.x;
    const int lane = tid & 63;
    const int w = tid >> 6;
    if (tid == 0) { carry_s = 0; row_ptr[0] = 0; }
    __syncthreads();
    for (int base = 0; base < N_NODES; base += 1024) {
        int i = base + tid;
        int v = (i < N_NODES) ? cnt[i] : 0;
        int sc = v;
        #pragma unroll
        for (int off = 1; off < 64; off <<= 1) {
            int t = __shfl_up(sc, off);
            if (lane >= off) sc += t;
        }
        if (lane == 63) wsum[w] = sc;
        __syncthreads();
        if (w == 0 && lane < 16) {
            int t = wsum[lane];
            int s2 = t;
            #pragma unroll
            for (int off = 1; off < 16; off <<= 1) {
                int u = __shfl_up(s2, off);
                if (lane >= off) s2 += u;
            }
            wsum[lane] = s2 - t;
        }
        __syncthreads();
        int incl = sc + wsum[w] + carry_s;
        if (i < N_NODES) row_ptr[i + 1] = incl;
        __syncthreads();
        if (tid == 1023) carry_s = incl;
        __syncthreads();
    }
}

// scatter edges into CSR order as packed (src, val_bits) uint2 — ONE 8B store
__global__ __launch_bounds__(256) void scatter_kernel(const int* __restrict__ src,
                                                      const int* __restrict__ dst,
                                                      const float* __restrict__ val,
                                                      const int* __restrict__ row_ptr,
                                                      int* __restrict__ cnt,
                                                      uint2* __restrict__ edges) {
    int i = blockIdx.x * 256 + threadIdx.x;
    if (i < N_EDGES) {
        int d   = dst[i];
        int pos = row_ptr[d] + atomicAdd(&cnt[d], 1);
        uint2 p;
        p.x = (uint)src[i];
        p.y = __builtin_bit_cast(uint, val[i]);
        edges[pos] = p;
    }
}

// ---------------------------------------------------------------------------
// bf16 MFMA GEMM, 128x256 tile, 512 threads (8 waves 2x4, each 64x64),
// 2-phase double-buffered (R9 structure — best ledger entry for this shape).
__global__ __launch_bounds__(512) void gemm_bf16_wide(const ushort* __restrict__ A, int lda,
                                                      const ushort* __restrict__ Bt, int ldb,
                                                      ushort* __restrict__ C, int ldc,
                                                      int M, int K) {
    __shared__ short As[2][128 * 32];
    __shared__ short Bs[2][256 * 32];
    const int tid  = threadIdx.x;
    const int lane = tid & 63;
    const int wid  = tid >> 6;
    const int wr   = wid >> 2;          // 0..1
    const int wc   = wid & 3;           // 0..3
    const int bm   = blockIdx.x * 128;

    f32x4 acc[4][4] = {};
    const int r0 = tid >> 2, ko = (tid & 3) * 8;   // r0: 0..127, ko: 0/8/16/24

    const ushort* gA  = A  + (size_t)(bm + r0) * lda + ko;
    const ushort* gB0 = Bt + (size_t)r0 * ldb + ko;
    const ushort* gB1 = Bt + (size_t)(128 + r0) * ldb + ko;

#define STAGE_WIDE(buf, kk) do { \
    __builtin_amdgcn_global_load_lds((const __attribute__((address_space(1))) void*)(gA + (kk)), \
        (__attribute__((address_space(3))) void*)&As[buf][tid * 8], 16, 0, 0); \
    __builtin_amdgcn_global_load_lds((const __attribute__((address_space(1))) void*)(gB0 + (kk)), \
        (__attribute__((address_space(3))) void*)&Bs[buf][tid * 8], 16, 0, 0); \
    __builtin_amdgcn_global_load_lds((const __attribute__((address_space(1))) void*)(gB1 + (kk)), \
        (__attribute__((address_space(3))) void*)&Bs[buf][(tid + 512) * 8], 16, 0, 0); \
} while (0)

    STAGE_WIDE(0, 0);
    __syncthreads();                    // buf 0 ready

    const int kg = (lane >> 4) * 8;
    const int rr = lane & 15;
    int cur = 0;
    for (int k0 = 0; k0 < K; k0 += 32) {
        if (k0 + 32 < K) STAGE_WIDE(cur ^ 1, k0 + 32);   // prefetch next tile
        bf16x8s a[4], b[4];
        #pragma unroll
        for (int i = 0; i < 4; ++i)
            a[i] = *(const bf16x8s*)&As[cur][(wr * 64 + i * 16 + rr) * 32 + kg];
        #pragma unroll
        for (int j = 0; j < 4; ++j)
            b[j] = *(const bf16x8s*)&Bs[cur][(wc * 64 + j * 16 + rr) * 32 + kg];
        #pragma unroll
        for (int i = 0; i < 4; ++i)
            #pragma unroll
            for (int j = 0; j < 4; ++j)
                acc[i][j] = __builtin_amdgcn_mfma_f32_16x16x32_bf16(a[i], b[j], acc[i][j], 0, 0, 0);
        __syncthreads();
        cur ^= 1;
    }
#undef STAGE_WIDE

    // epilogue: D row=(lane>>4)*4+r, col=lane&15  [m89 verified mapping]
    const int rowg = (lane >> 4) * 4;
    const int colg = lane & 15;
    #pragma unroll
    for (int i = 0; i < 4; ++i) {
        #pragma unroll
        for (int j = 0; j < 4; ++j) {
            #pragma unroll
            for (int r = 0; r < 4; ++r) {
                int row = bm + wr * 64 + i * 16 + rowg + r;
                int col = wc * 64 + j * 16 + colg;
                if (row < M) C[(size_t)row * ldc + col] = f2bf(acc[i][j][r]);
            }
        }
    }
}

// bf16 MFMA GEMM, 128x64 tile — out layer only. 256 threads, 4 waves 2x2,
// each wave 64x32 (acc[4][2]). Wt_out is 64 rows (cols 40..63 zero), so no
// wasted MFMA work on the 128-col padding the old 128x128 kernel computed.
__global__ __launch_bounds__(256) void gemm_bf16_out(const ushort* __restrict__ A, int lda,
                                                     const ushort* __restrict__ Bt, int ldb,
                                                     ushort* __restrict__ C,   // [M][64]
                                                     int M, int K) {
    __shared__ short As[128 * 32];
    __shared__ short Bs[64 * 32];
    const int tid  = threadIdx.x;
    const int lane = tid & 63;
    const int wid  = tid >> 6;
    const int wr   = wid >> 1;          // 0..1
    const int wc   = wid & 1;           // 0..1
    const int bm   = blockIdx.x * 128;

    f32x4 acc[4][2] = {};
    const int r0 = tid >> 2, ko = (tid & 3) * 8;   // r0: 0..63, ko: 0/8/16/24

    for (int k0 = 0; k0 < K; k0 += 32) {
        {
            const ushort* g0 = A + (size_t)(bm + r0) * lda + k0 + ko;
            const ushort* g1 = A + (size_t)(bm + 64 + r0) * lda + k0 + ko;
            __builtin_amdgcn_global_load_lds((const __attribute__((address_space(1))) void*)g0,
                                             (__attribute__((address_space(3))) void*)&As[tid * 8], 16, 0, 0);
            __builtin_amdgcn_global_load_lds((const __attribute__((address_space(1))) void*)g1,
                                             (__attribute__((address_space(3))) void*)&As[(tid + 256) * 8], 16, 0, 0);
        }
        {
            const ushort* gb = Bt + (size_t)r0 * ldb + k0 + ko;   // rows 0..63
            __builtin_amdgcn_global_load_lds((const __attribute__((address_space(1))) void*)gb,
                                             (__attribute__((address_space(3))) void*)&Bs[tid * 8], 16, 0, 0);
        }
        __syncthreads();

        const int kg = (lane >> 4) * 8;
        const int rr = lane & 15;
        bf16x8s a[4], b[2];
        #pragma unroll
        for (int i = 0; i < 4; ++i)
            a[i] = *(const bf16x8s*)&As[(wr * 64 + i * 16 + rr) * 32 + kg];
        #pragma unroll
        for (int j = 0; j < 2; ++j)
            b[j] = *(const bf16x8s*)&Bs[(wc * 32 + j * 16 + rr) * 32 + kg];
        #pragma unroll
        for (int i = 0; i < 4; ++i)
            #pragma unroll
            for (int j = 0; j < 2; ++j)
                acc[i][j] = __builtin_amdgcn_mfma_f32_16x16x32_bf16(a[i], b[j], acc[i][j], 0, 0, 0);
        __syncthreads();
    }

    const int rowg = (lane >> 4) * 4;
    const int colg = lane & 15;
    #pragma unroll
    for (int i = 0; i < 4; ++i) {
        #pragma unroll
        for (int j = 0; j < 2; ++j) {
            #pragma unroll
            for (int r = 0; r < 4; ++r) {
                int row = bm + wr * 64 + i * 16 + rowg + r;
                int col = wc * 32 + j * 16 + colg;
                if (row < M) C[(size_t)row * 64 + col] = f2bf(acc[i][j][r]);
            }
        }
    }
}

// ---------------------------------------------------------------------------
// CSR spmm, 256-wide bf16 features, one wave/node.
// CLOSED at ~105 us: random-gather L2-miss floor (350 MB @ ~3.6 TB/s).
// Col-split, XCD-pinning, src-ordering, explicit SW pipeline all falsified.
__global__ __launch_bounds__(256) void spmm256_tanh_kernel(const int* __restrict__ row_ptr,
                                                           const uint2* __restrict__ edges,
                                                           const ushort* __restrict__ Zb, // [N,256] bf16
                                                           const float* __restrict__ bias,
                                                           ushort* __restrict__ out,      // Hb + col_off
                                                           int out_stride) {
    int node = blockIdx.x * 4 + (threadIdx.x >> 6);
    if (node >= N_NODES) return;
    int lane = threadIdx.x & 63;
    int s = row_ptr[node], e = row_ptr[node + 1];
    const ushort4* Z4 = (const ushort4*)Zb;   // 4 cols / lane
    float ax = 0.f, ay = 0.f, az = 0.f, aw = 0.f;
    int i = s;

    if (e - s >= 16) {
        uint2   ed[8];
        float   vaA[8], vaB[8];
        ushort4 xvA[8], xvB[8];
        #pragma unroll
        for (int u = 0; u < 8; ++u) ed[u] = edges[i + u];
        #pragma unroll
        for (int u = 0; u < 8; ++u) {
            vaA[u] = __builtin_bit_cast(float, ed[u].y);
            xvA[u] = Z4[(size_t)ed[u].x * 64 + lane];
        }
        #pragma unroll
        for (int u = 0; u < 8; ++u) ed[u] = edges[i + 8 + u];

        while (i + 32 <= e) {
            #pragma unroll
            for (int u = 0; u < 8; ++u) {
                vaB[u] = __builtin_bit_cast(float, ed[u].y);
                xvB[u] = Z4[(size_t)ed[u].x * 64 + lane];
            }
            #pragma unroll
            for (int u = 0; u < 8; ++u) ed[u] = edges[i + 16 + u];
            #pragma unroll
            for (int u = 0; u < 8; ++u) {
                ax += vaA[u] * bf2f(xvA[u].x); ay += vaA[u] * bf2f(xvA[u].y);
                az += vaA[u] * bf2f(xvA[u].z); aw += vaA[u] * bf2f(xvA[u].w);
            }
            #pragma unroll
            for (int u = 0; u < 8; ++u) {
                vaA[u] = __builtin_bit_cast(float, ed[u].y);
                xvA[u] = Z4[(size_t)ed[u].x * 64 + lane];
            }
            #pragma unroll
            for (int u = 0; u < 8; ++u) ed[u] = edges[i + 24 + u];
            #pragma unroll
            for (int u = 0; u < 8; ++u) {
                ax += vaB[u] * bf2f(xvB[u].x); ay += vaB[u] * bf2f(xvB[u].y);
                az += vaB[u] * bf2f(xvB[u].z); aw += vaB[u] * bf2f(xvB[u].w);
            }
            i += 16;
        }
        #pragma unroll
        for (int u = 0; u < 8; ++u) {
            vaB[u] = __builtin_bit_cast(float, ed[u].y);
            xvB[u] = Z4[(size_t)ed[u].x * 64 + lane];
        }
        #pragma unroll
        for (int u = 0; u < 8; ++u) {
            ax += vaA[u] * bf2f(xvA[u].x); ay += vaA[u] * bf2f(xvA[u].y);
            az += vaA[u] * bf2f(xvA[u].z); aw += vaA[u] * bf2f(xvA[u].w);
        }
        #pragma unroll
        for (int u = 0; u < 8; ++u) {
            ax += vaB[u] * bf2f(xvB[u].x); ay += vaB[u] * bf2f(xvB[u].y);
            az += vaB[u] * bf2f(xvB[u].z); aw += vaB[u] * bf2f(xvB[u].w);
        }
        i += 16;
    }
    for (; i + 4 <= e; i += 4) {
        uint2 ed[4]; ushort4 xv[4];
        #pragma unroll
        for (int u = 0; u < 4; ++u) ed[u] = edges[i + u];
        #pragma unroll
        for (int u = 0; u < 4; ++u) xv[u] = Z4[(size_t)ed[u].x * 64 + lane];
        #pragma unroll
        for (int u = 0; u < 4; ++u) {
            float v = __builtin_bit_cast(float, ed[u].y);
            ax += v * bf2f(xv[u].x); ay += v * bf2f(xv[u].y);
            az += v * bf2f(xv[u].z); aw += v * bf2f(xv[u].w);
        }
    }
    for (; i < e; ++i) {
        uint2 ed = edges[i];
        float v = __builtin_bit_cast(float, ed.y);
        ushort4 x0 = Z4[(size_t)ed.x * 64 + lane];
        ax += v * bf2f(x0.x); ay += v * bf2f(x0.y);
        az += v * bf2f(x0.z); aw += v * bf2f(x0.w);
    }
    float4 b = ((const float4*)bias)[lane];
    ushort4 o;
    o.x = f2bf(tanhf(ax + b.x)); o.y = f2bf(tanhf(ay + b.y));
    o.z = f2bf(tanhf(az + b.z)); o.w = f2bf(tanhf(aw + b.w));
    *(ushort4*)&out[(size_t)node * out_stride + lane * 4] = o;
}

// out-layer: spmm (Zout bf16, stride 64, cols 40..63 zero) + bias + log_softmax.
__global__ __launch_bounds__(256) void spmm_out_lsm_kernel(const int* __restrict__ row_ptr,
                                                           const uint2* __restrict__ edges,
                                                           const ushort* __restrict__ Zb, // [N,64]
                                                           const float* __restrict__ bias,
                                                           float* __restrict__ out) { // [N,40]
    int node = blockIdx.x * 4 + (threadIdx.x >> 6);
    if (node >= N_NODES) return;
    int lane = threadIdx.x & 63;
    int e8 = lane >> 3;     // edge slot 0..7
    int cg = lane & 7;      // col group: cols cg*8 .. cg*8+7
    int s = row_ptr[node], e = row_ptr[node + 1];
    float acc[8] = {};
    int i = s;
    for (; i + 8 <= e; i += 8) {
        uint2 ed = edges[i + e8];
        float v  = __builtin_bit_cast(float, ed.y);
        bf16x8s x = *(const bf16x8s*)&Zb[(size_t)ed.x * 64 + cg * 8];
        #pragma unroll
        for (int u = 0; u < 8; ++u) acc[u] += v * bf2f((ushort)x[u]);
    }
    if (i + e8 < e) {
        uint2 ed = edges[i + e8];
        float v  = __builtin_bit_cast(float, ed.y);
        bf16x8s x = *(const bf16x8s*)&Zb[(size_t)ed.x * 64 + cg * 8];
        #pragma unroll
        for (int u = 0; u < 8; ++u) acc[u] += v * bf2f((ushort)x[u]);
    }
    #pragma unroll
    for (int off = 8; off < 64; off <<= 1)
        #pragma unroll
        for (int u = 0; u < 8; ++u) acc[u] += __shfl_xor(acc[u], off);
    float m = -INFINITY;
    #pragma unroll
    for (int u = 0; u < 8; ++u) {
        int col = cg * 8 + u;
        if (col < NCLASS) { acc[u] += bias[col]; m = fmaxf(m, acc[u]); }
    }
    #pragma unroll
    for (int off = 1; off < 8; off <<= 1) m = fmaxf(m, __shfl_xor(m, off));
    float ss = 0.f;
    #pragma unroll
    for (int u = 0; u < 8; ++u) {
        int col = cg * 8 + u;
        if (col < NCLASS) ss += expf(acc[u] - m);
    }
    #pragma unroll
    for (int off = 1; off < 8; off <<= 1) ss += __shfl_xor(ss, off);
    float lse = logf(ss);
    if (e8 == 0) {
        #pragma unroll
        for (int u = 0; u < 8; ++u) {
            int col = cg * 8 + u;
            if (col < NCLASS) out[(size_t)node * NCLASS + col] = acc[u] - m - lse;
        }
    }
}

// ---------------------------------------------------------------------------
extern "C" void kernel_launch(void* const* d_in, const int* in_sizes, int n_in,
                              void* d_out, int out_size, void* d_ws, size_t ws_size,
                              hipStream_t stream) {
    const float* x        = (const float*)d_in[0];
    const float* edge_val = (const float*)d_in[1];
    const int*   edge_src = (const int*)d_in[2];
    const int*   edge_dst = (const int*)d_in[3];
    const float* W[4]     = {(const float*)d_in[4], (const float*)d_in[6],
                             (const float*)d_in[8], (const float*)d_in[10]};
    const float* bvec[4]  = {(const float*)d_in[5], (const float*)d_in[7],
                             (const float*)d_in[9], (const float*)d_in[11]};
    const float* W_out    = (const float*)d_in[12];
    const float* b_out    = (const float*)d_in[13];
    float* out = (float*)d_out;

    // workspace carve-up (bytes)
    char* ws = (char*)d_ws;
    ushort* Hb     = (ushort*)ws;                          // 153.6 MB
    ushort* Zb     = (ushort*)(ws + 153600000);            // 25.6 MB
    ushort* Zoutb  = (ushort*)(ws + 179200000);            // 6.4 MB
    ushort* Wt[4]  = {(ushort*)(ws + 185600000),
                      (ushort*)(ws + 185862144),
                      (ushort*)(ws + 186255360),
                      (ushort*)(ws + 186779648)};
    ushort* Wt_out = (ushort*)(ws + 187435008);            // 64 x 1536 bf16
    uint2*  edges  = (uint2*) (ws + 187828224);            // 12.8 MB packed (src,val)
    int*    row_ptr= (int*)   (ws + 200628224);
    int*    cnt    = (int*)   (ws + 200828228);

    // 1. CSR build
    hipMemsetAsync(cnt, 0, N_NODES * sizeof(int), stream);
    hist_kernel<<<(N_EDGES + 255) / 256, 256, 0, stream>>>(edge_dst, cnt);
    scan_kernel<<<1, 1024, 0, stream>>>(cnt, row_ptr);
    hipMemsetAsync(cnt, 0, N_NODES * sizeof(int), stream);
    scatter_kernel<<<(N_EDGES + 255) / 256, 256, 0, stream>>>(
        edge_src, edge_dst, edge_val, row_ptr, cnt, edges);

    // 2. weights -> bf16 transposed, x -> Hb
    convert_weights_kernel<<<2048, 256, 0, stream>>>(W[0], W[1], W[2], W[3], W_out,
                                                     Wt[0], Wt[1], Wt[2], Wt[3], Wt_out);
    copy_x_bf16_kernel<<<4096, 256, 0, stream>>>((const float4*)x, Hb);

    // 3. snowball layers — 128x256 dbuf GEMM, A read once per layer
    for (int k = 0; k < 4; ++k) {
        int fan_in = NFEAT + k * NHID;
        gemm_bf16_wide<<<(N_NODES + 127) / 128, 512, 0, stream>>>(
            Hb, HCOLS, Wt[k], fan_in, Zb, NHID, N_NODES, fan_in);
        spmm256_tanh_kernel<<<(N_NODES + 3) / 4, 256, 0, stream>>>(
            row_ptr, edges, Zb, bvec[k], Hb + NFEAT + k * NHID, HCOLS);
    }

    // 4. out layer — 128x64 tile (no padded-column waste)
    {
        gemm_bf16_out<<<(N_NODES + 127) / 128, 256, 0, stream>>>(
            Hb, HCOLS, Wt_out, HCOLS, Zoutb, N_NODES, HCOLS);
        spmm_out_lsm_kernel<<<(N_NODES + 3) / 4, 256, 0, stream>>>(
            row_ptr, edges, Zoutb, b_out, out);
    }
    (void)in_sizes; (void)n_in; (void)out_size; (void)ws_size;
}